// Round 7
// baseline (88.707 us; speedup 1.0000x reference)
//
#include <hip/hip_runtime.h>
#include <hip/hip_bf16.h>

// Problem constants: B=128, C=21, L=2048, W=32, S=8, O=16, NW=252, NK=4032, K=672
#define Bb   128
#define Cc   21
#define Ll   2048
#define Ss   8
#define Oo   16
#define NWw  252
#define NKk  4032
#define Kk   672

typedef __attribute__((ext_vector_type(8))) short  short8;  // 8 bf16 = 4 VGPRs
typedef __attribute__((ext_vector_type(4))) float  f32x4;

static __device__ __forceinline__ unsigned short f2bf(float f) {
    union { __hip_bfloat16 h; unsigned short u; } cv;
    cv.h = __float2bfloat16(f);
    return cv.u;
}

static __device__ __forceinline__ short8 cvt8(const float4 a0, const float4 a1) {
    short8 a;
    a[0] = (short)f2bf(a0.x); a[1] = (short)f2bf(a0.y);
    a[2] = (short)f2bf(a0.z); a[3] = (short)f2bf(a0.w);
    a[4] = (short)f2bf(a1.x); a[5] = (short)f2bf(a1.y);
    a[6] = (short)f2bf(a1.z); a[7] = (short)f2bf(a1.w);
    return a;
}

// Single dispatch, ZERO LDS, ZERO barriers: pure load->cvt->MFMA dataflow.
// Every prior version paid a weight-stage -> __syncthreads -> compute latency
// wall per block; R3/R5/R6 showed more waves / more MLP / co-residency are all
// neutral, so the residual is serialization, not starvation. Here each wave
// loads its own B-fragments from global fp32 (lane reads w-row `col`, 32 B
// contiguous; 4x intra-block redundancy is L2-served). HBM bytes are the
// schedule-independent minimum: x 22 + w 10.8 + out 2 = 35 MB.
// Grid 512 = 252 windows x 2 batch-halves, R4's validated XCD grouping:
// XCD r = bid%8 owns windows [32r, 32r+32) -> x slab L2-resident.
__global__ __launch_bounds__(256, 4)
void fb_fwd(const float* __restrict__ x, const float* __restrict__ w,
            float* __restrict__ out) {
    const int bid = blockIdx.x;
    const int r   = bid & 7;                  // XCD id (dispatch heuristic)
    const int t2  = bid >> 3;                 // 0..63 within XCD
    const int j   = r * 32 + (t2 >> 1);
    const int bh  = t2 & 1;                   // batch half
    if (j >= NWw) return;                     // uniform per block

    const int s    = (j < NWw - 1) ? j * Ss : (Ll - 32);  // STARTS[j], mult of 8
    const int tid  = threadIdx.x;
    const int lane = tid & 63;
    const int wv   = tid >> 6;       // 0..3: m-tile id (16 batch rows)
    const int col  = lane & 15;      // MFMA m-row (A) / n-col (B = w-row o)
    const int quad = lane >> 4;      // k-chunk selector

    // A source: batch row (bh*64 + wv*16 + col), k = c*32 + quad*8 .. +8
    const float* xrow = x + ((size_t)(bh * 64 + wv * 16 + col) * Cc) * Ll
                          + s + quad * 8;
    // B source: weight row `col` of window j, same k indexing (B^T layout)
    const float* wrow = w + (size_t)j * Oo * Kk + (size_t)col * Kk + quad * 8;

    f32x4 acc = {0.f, 0.f, 0.f, 0.f};
#pragma unroll
    for (int c = 0; c < Cc; ++c) {                 // 21 k-steps of 32
        const float4 a0 = *(const float4*)(xrow + (size_t)c * Ll);
        const float4 a1 = *(const float4*)(xrow + (size_t)c * Ll + 4);
        const float4 b0 = *(const float4*)(wrow + c * 32);
        const float4 b1 = *(const float4*)(wrow + c * 32 + 4);
        acc = __builtin_amdgcn_mfma_f32_16x16x32_bf16(
            cvt8(a0, a1), cvt8(b0, b1), acc, 0, 0, 0);
    }

    // C/D layout: col = lane&15, row = quad*4 + reg
    const int rbase = bh * 64 + wv * 16 + quad * 4;
    float* op = out + (size_t)rbase * NKk + j * 16 + col;
#pragma unroll
    for (int rr = 0; rr < 4; ++rr)
        op[(size_t)rr * NKk] = acc[rr];
}

extern "C" void kernel_launch(void* const* d_in, const int* in_sizes, int n_in,
                              void* d_out, int out_size, void* d_ws, size_t ws_size,
                              hipStream_t stream) {
    const float* x = (const float*)d_in[0];   // (128, 21, 2048) fp32
    const float* w = (const float*)d_in[1];   // (4032, 672) fp32
    float* out = (float*)d_out;               // (128, 4032) fp32
    fb_fwd<<<dim3(512), dim3(256), 0, stream>>>(x, w, out);
}

// Round 8
// 83.738 us; speedup vs baseline: 1.0593x; 1.0593x over previous
//
#include <hip/hip_runtime.h>
#include <hip/hip_bf16.h>

// Problem constants: B=128, C=21, L=2048, W=32, S=8, O=16, NW=252, NK=4032, K=672
#define Bb   128
#define Cc   21
#define Ll   2048
#define Ss   8
#define Oo   16
#define NWw  252
#define NKk  4032
#define Kk   672
#define KP   680   // LDS pitch (bf16): 85 x 16B granules/row, conflict-light b128

typedef __attribute__((ext_vector_type(8))) short  short8;  // 8 bf16 = 4 VGPRs
typedef __attribute__((ext_vector_type(4))) float  f32x4;

static __device__ __forceinline__ unsigned short f2bf(float f) {
    union { __hip_bfloat16 h; unsigned short u; } cv;
    cv.h = __float2bfloat16(f);
    return cv.u;
}

static __device__ __forceinline__ short8 cvt8(const float4 a0, const float4 a1) {
    short8 a;
    a[0] = (short)f2bf(a0.x); a[1] = (short)f2bf(a0.y);
    a[2] = (short)f2bf(a0.z); a[3] = (short)f2bf(a0.w);
    a[4] = (short)f2bf(a1.x); a[5] = (short)f2bf(a1.y);
    a[6] = (short)f2bf(a1.z); a[7] = (short)f2bf(a1.w);
    return a;
}

// Single dispatch, minimum compulsory bytes (x 22 + w 10.8 + out 2 = 35 MB).
// Ledger across R1-R7: only byte reduction + XCD/L2 locality ever helped;
// occupancy/MLP/DMA/barrier levers all neutral -> harness's 256 MB ws-poison
// runs right before us and sweeps L2+L3, so we're cold-HBM-latency floored.
// Structure = R5's best fb_mm, minus the cvt_x pre-pass (ws round-trip) :
//  - grid 256 (252 windows + 4 idle), XCD r=bid%8 owns windows [32r,32r+32)
//    -> 3.1 MB fp32 x-slab per XCD L2-resident for the 4x overlap re-read.
//  - 512 thr = 8 waves x 16-batch m-tiles = all 128 batches; w staged ONCE
//    per window (R7 showed per-wave B redundancy costs ~4 us).
//  - weight fp32 -> bf16 -> LDS [o][k], KP=680 pitch; one barrier total.
//  - A-slice batch-issued BEFORE the barrier: 21 float4-pairs in flight
//    (no launch_bounds cap; 1 blk/CU is fine per R3/R6 neutrality), cvt to
//    21 bf16 frags, then a pure 21-MFMA register sweep.
__global__ __launch_bounds__(512)
void fb_fwd(const float* __restrict__ x, const float* __restrict__ w,
            float* __restrict__ out) {
    __shared__ unsigned short ws[Oo * KP];   // 21.8 KB

    const int bid = blockIdx.x;
    const int j   = (bid & 7) * 32 + (bid >> 3);          // XCD-grouped window
    if (j >= NWw) return;                                  // 4 tail blocks idle
    const int s    = (j < NWw - 1) ? j * Ss : (Ll - 32);  // STARTS[j], mult of 8
    const int tid  = threadIdx.x;
    const int lane = tid & 63;
    const int wv   = tid >> 6;       // 0..7: m-tile id (16 batch rows)
    const int col  = lane & 15;      // MFMA m-row (A) / n-col (B = w-row o)
    const int quad = lane >> 4;      // k-chunk selector

    // ---- batch-issue the whole A-slice (21 x 32 B fp32, all in flight) ----
    const float* xrow = x + ((size_t)(wv * 16 + col) * Cc) * Ll + s + quad * 8;
    float4 a0[Cc], a1[Cc];
#pragma unroll
    for (int c = 0; c < Cc; ++c) {
        a0[c] = *(const float4*)(xrow + (size_t)c * Ll);
        a1[c] = *(const float4*)(xrow + (size_t)c * Ll + 4);
    }

    // ---- stage weight[j]: 16 x 672 fp32 -> bf16 LDS, [o][k] (B^T) ----
    {
        const float4* wj4 = (const float4*)(w + (size_t)j * Oo * Kk);
        for (int t = tid; t < Oo * (Kk / 4); t += 512) {   // 2688 float4
            float4 v = wj4[t];
            int o = t / (Kk / 4);                           // Kk/4 = 168
            int r = t - o * (Kk / 4);
            *(ushort4*)&ws[o * KP + r * 4] =
                make_ushort4(f2bf(v.x), f2bf(v.y), f2bf(v.z), f2bf(v.w));
        }
    }

    // cvt A to bf16 frags while the stage drains
    short8 afr[Cc];
#pragma unroll
    for (int c = 0; c < Cc; ++c) afr[c] = cvt8(a0[c], a1[c]);

    __syncthreads();

    const unsigned short* wrow = &ws[col * KP + quad * 8];
    f32x4 acc = {0.f, 0.f, 0.f, 0.f};
#pragma unroll
    for (int c = 0; c < Cc; ++c)
        acc = __builtin_amdgcn_mfma_f32_16x16x32_bf16(
            afr[c], *(const short8*)(wrow + c * 32), acc, 0, 0, 0);

    // ---- C/D layout: col = lane&15, row = quad*4 + reg ----
    const int rbase = wv * 16 + quad * 4;
    float* op = out + (size_t)rbase * NKk + j * 16 + col;
#pragma unroll
    for (int r = 0; r < 4; ++r)
        op[(size_t)r * NKk] = acc[r];
}

extern "C" void kernel_launch(void* const* d_in, const int* in_sizes, int n_in,
                              void* d_out, int out_size, void* d_ws, size_t ws_size,
                              hipStream_t stream) {
    const float* x = (const float*)d_in[0];   // (128, 21, 2048) fp32
    const float* w = (const float*)d_in[1];   // (4032, 672) fp32
    float* out = (float*)d_out;               // (128, 4032) fp32
    fb_fwd<<<dim3(256), dim3(512), 0, stream>>>(x, w, out);
}